// Round 8
// baseline (1895.586 us; speedup 1.0000x reference)
//
#include <hip/hip_runtime.h>
#include <hip/hip_fp16.h>

#define TT 1024
#define BB 128
#define II 256
#define HH 256
#define NG 768   // 3*H

// Static scratch (ws_size unknown): x bf16, wih^T bf16, gi f16.
__device__ __align__(16) unsigned short g_xbf[(size_t)TT * BB * II];   // 67 MB
__device__ __align__(16) unsigned short g_wihB[NG * II];               // 384 KB, [n][k]
__device__ __align__(16) _Float16       g_gi[(size_t)TT * BB * NG];    // 201 MB f16

typedef __attribute__((ext_vector_type(8))) short    bfrag;   // 8 bf16 = 4 VGPR
typedef __attribute__((ext_vector_type(8))) _Float16 hfrag;   // 8 f16  = 4 VGPR
typedef __attribute__((ext_vector_type(4))) float    f32x4;

__device__ __forceinline__ unsigned short f2bf(float f) {
    unsigned u = __float_as_uint(f);
    return (unsigned short)((u + 0x7fffu + ((u >> 16) & 1u)) >> 16);   // RNE
}

// ---------------- phase 1a: x f32 -> bf16 ----------------
__global__ void cvt_x_kernel(const float* __restrict__ x) {
    const int n4 = TT * BB * II / 4;
    for (int i = blockIdx.x * blockDim.x + threadIdx.x; i < n4;
         i += gridDim.x * blockDim.x) {
        float4 v = reinterpret_cast<const float4*>(x)[i];
        ushort4 o;
        o.x = f2bf(v.x); o.y = f2bf(v.y); o.z = f2bf(v.z); o.w = f2bf(v.w);
        reinterpret_cast<ushort4*>(g_xbf)[i] = o;
    }
}

// ---------------- phase 1b: wihT [k][n] f32 -> wihB [n][k] bf16 ----------------
__global__ void cvt_wih_kernel(const float* __restrict__ wihT) {
    const int n = blockIdx.x;    // 0..767
    const int k = threadIdx.x;   // 0..255
    g_wihB[n * II + k] = f2bf(wihT[k * NG + n]);
}

// ---------------- phase 2: gi = x @ wihT  (MFMA bf16, f16 out) ----------------
__global__ void __launch_bounds__(256) gi_gemm_kernel() {
    __shared__ unsigned short Ab[128 * 32];
    __shared__ unsigned short Bb[128 * 32];
    const int tid = threadIdx.x;
    const int mt = blockIdx.x / 6, nt = blockIdx.x % 6;
    const int m0 = mt * 128, n0 = nt * 128;
    const int l = tid & 63, w = tid >> 6;
    const int wr = w >> 1, wc = w & 1;
    const int srow = tid >> 2, scol = (tid & 3) * 8;

    f32x4 acc[4][4] = {};

    for (int ks = 0; ks < 8; ++ks) {
        const int k0 = ks * 32;
        __syncthreads();
        #pragma unroll
        for (int c = 0; c < 2; ++c) {
            const int row = c * 64 + srow;
            *reinterpret_cast<uint4*>(&Ab[row * 32 + scol]) =
                *reinterpret_cast<const uint4*>(&g_xbf[(size_t)(m0 + row) * II + k0 + scol]);
            *reinterpret_cast<uint4*>(&Bb[row * 32 + scol]) =
                *reinterpret_cast<const uint4*>(&g_wihB[(n0 + row) * II + k0 + scol]);
        }
        __syncthreads();
        bfrag af[4], bf[4];
        #pragma unroll
        for (int i = 0; i < 4; ++i) {
            af[i] = *reinterpret_cast<const bfrag*>(
                        &Ab[(wr * 64 + i * 16 + (l & 15)) * 32 + (l >> 4) * 8]);
            bf[i] = *reinterpret_cast<const bfrag*>(
                        &Bb[(wc * 64 + i * 16 + (l & 15)) * 32 + (l >> 4) * 8]);
        }
        #pragma unroll
        for (int mi = 0; mi < 4; ++mi)
            #pragma unroll
            for (int ni = 0; ni < 4; ++ni)
                acc[mi][ni] = __builtin_amdgcn_mfma_f32_16x16x32_bf16(
                                  af[mi], bf[ni], acc[mi][ni], 0, 0, 0);
    }
    #pragma unroll
    for (int mi = 0; mi < 4; ++mi) {
        const int grow = m0 + wr * 64 + mi * 16 + (l >> 4) * 4;
        #pragma unroll
        for (int ni = 0; ni < 4; ++ni) {
            const int gcol = n0 + wc * 64 + ni * 16 + (l & 15);
            #pragma unroll
            for (int q = 0; q < 4; ++q)
                g_gi[(size_t)(grow + q) * NG + gcol] = (_Float16)acc[mi][ni][q];
        }
    }
}

// ---------------- phase 3: recurrence via MFMA, whh in B-fragments ----------------
// 128 WGs (one batch row) x 1024 threads (16 waves). Wave w owns j in
// [16w,16w+16) x {r,z,n}: 24 B-frags (f16) = 96 VGPR/lane held as MFMA
// operands. A = h as a 1x256 row: only LDS row 0 exists (1 KB ping-pong);
// A-frags are built by a 4-segment broadcast ds_read (addr depends only on
// g = lane>>4) + cndmask zeroing lanes ln15 != 0 -- rows 1..15 of A are
// exact zeros, never stored, never read. C row 0 (lanes 0-15, reg 0) is gh.
// gi (f16, L3-resident) register-prefetched one step ahead.
#define LDB(NAME, CB, KT)                                                   \
    hfrag NAME;                                                             \
    _Pragma("unroll")                                                       \
    for (int e = 0; e < 8; ++e)                                             \
        NAME[e] = (_Float16)whhT[(size_t)((KT) * 32 + g * 8 + e) * NG + (CB) + ln15];

#define KSTEP(KT)                                                           \
    {                                                                       \
        const hfrag Av = *reinterpret_cast<const hfrag*>(hl + (KT) * 32 + (g << 3)); \
        const hfrag A  = (ln15 == 0) ? Av : hz;                             \
        accR = __builtin_amdgcn_mfma_f32_16x16x32_f16(A, BR##KT, accR, 0, 0, 0); \
        accZ = __builtin_amdgcn_mfma_f32_16x16x32_f16(A, BZ##KT, accZ, 0, 0, 0); \
        accN = __builtin_amdgcn_mfma_f32_16x16x32_f16(A, BN##KT, accN, 0, 0, 0); \
    }

__global__ void __launch_bounds__(1024) gru_rec_kernel(
    const float* __restrict__ h0, const float* __restrict__ whhT,
    const float* __restrict__ bias, float* __restrict__ out)
{
    __shared__ __align__(16) _Float16 hbuf[2][HH];   // 1 KB ping-pong h (f16)

    const int tid  = threadIdx.x;
    const int b    = blockIdx.x;
    const int w    = tid >> 6;          // wave 0..15
    const int l    = tid & 63;
    const int g    = l >> 4;            // k-chunk group 0..3
    const int ln15 = l & 15;            // B-col offset / A-row
    const int jb   = w << 4;            // wave's j base
    const int jj   = jb + ln15;         // this lane's j (used on g==0)

    // --- whh B-fragments: 3 gates x 8 k-tiles, named SSA (f16) ---
    LDB(BR0, jb, 0) LDB(BR1, jb, 1) LDB(BR2, jb, 2) LDB(BR3, jb, 3)
    LDB(BR4, jb, 4) LDB(BR5, jb, 5) LDB(BR6, jb, 6) LDB(BR7, jb, 7)
    LDB(BZ0, HH + jb, 0) LDB(BZ1, HH + jb, 1) LDB(BZ2, HH + jb, 2) LDB(BZ3, HH + jb, 3)
    LDB(BZ4, HH + jb, 4) LDB(BZ5, HH + jb, 5) LDB(BZ6, HH + jb, 6) LDB(BZ7, HH + jb, 7)
    LDB(BN0, 2*HH + jb, 0) LDB(BN1, 2*HH + jb, 1) LDB(BN2, 2*HH + jb, 2) LDB(BN3, 2*HH + jb, 3)
    LDB(BN4, 2*HH + jb, 4) LDB(BN5, 2*HH + jb, 5) LDB(BN6, 2*HH + jb, 6) LDB(BN7, 2*HH + jb, 7)

    const float br = bias[jj];
    const float bz = bias[HH + jj];
    const float bn = bias[2 * HH + jj];
    const hfrag hz = {};

    // --- init LDS row 0 with h0; hprev tracked in-register on g==0 lanes ---
    float hprev = h0[b * HH + jj];
    if (tid < 256) hbuf[0][tid] = (_Float16)h0[b * HH + tid];
    __syncthreads();

    // gi prefetch registers, primed for t=0
    const _Float16* gb0 = g_gi + (size_t)b * NG;
    float gR = (float)gb0[jj], gZ = (float)gb0[HH + jj], gN = (float)gb0[2 * HH + jj];

    for (int t = 0; t < TT; ++t) {
        const _Float16* hl  = hbuf[t & 1];
        _Float16*       hn_ = hbuf[(t & 1) ^ 1];

        // prefetch gi[t+1] (consumed next iteration)
        float nR = gR, nZ = gZ, nN = gN;
        if (t + 1 < TT) {
            const _Float16* gn = g_gi + ((size_t)(t + 1) * BB + b) * NG;
            nR = (float)gn[jj]; nZ = (float)gn[HH + jj]; nN = (float)gn[2 * HH + jj];
        }

        // gh = h @ whh for this wave's 16 j x 3 gates
        f32x4 accR = {0.f, 0.f, 0.f, 0.f};
        f32x4 accZ = {0.f, 0.f, 0.f, 0.f};
        f32x4 accN = {0.f, 0.f, 0.f, 0.f};
        KSTEP(0) KSTEP(1) KSTEP(2) KSTEP(3)
        KSTEP(4) KSTEP(5) KSTEP(6) KSTEP(7)

        // epilogue: C row 0 = acc*[0] on lanes g==0 (col = ln15)
        const float sR = accR[0] + gR + br;
        const float sZ = accZ[0] + gZ + bz;
        const float r  = 1.f / (1.f + __expf(-sR));
        const float z  = 1.f / (1.f + __expf(-sZ));
        const float e  = __expf(2.f * (gN + bn + r * accN[0]));   // tanh
        const float n  = 1.f - 2.f / (e + 1.f);
        const float hv = (1.f - z) * n + z * hprev;
        if (g == 0) {
            hprev = hv;
            hn_[jj] = (_Float16)hv;
            if (t == TT - 1) out[b * HH + jj] = hv;
        }

        gR = nR; gZ = nZ; gN = nN;
        __syncthreads();
    }
}

extern "C" void kernel_launch(void* const* d_in, const int* in_sizes, int n_in,
                              void* d_out, int out_size, void* d_ws, size_t ws_size,
                              hipStream_t stream) {
    const float* x    = (const float*)d_in[0];
    const float* h0   = (const float*)d_in[1];
    const float* wihT = (const float*)d_in[2];
    const float* whhT = (const float*)d_in[3];
    const float* bias = (const float*)d_in[4];
    float*       out  = (float*)d_out;

    cvt_x_kernel<<<2048, 256, 0, stream>>>(x);
    cvt_wih_kernel<<<NG, 256, 0, stream>>>(wihT);
    gi_gemm_kernel<<<1024 * 6, 256, 0, stream>>>();
    gru_rec_kernel<<<BB, 1024, 0, stream>>>(h0, whhT, bias, out);
}

// Round 9
// 1501.716 us; speedup vs baseline: 1.2623x; 1.2623x over previous
//
#include <hip/hip_runtime.h>
#include <hip/hip_fp16.h>

#define TT 1024
#define BB 128
#define II 256
#define HH 256
#define NG 768   // 3*H

// Static scratch (ws_size unknown): x bf16, wih^T bf16, gi f16 (bias folded in).
__device__ __align__(16) unsigned short g_xbf[(size_t)TT * BB * II];   // 67 MB
__device__ __align__(16) unsigned short g_wihB[NG * II];               // 384 KB, [n][k]
__device__ __align__(16) _Float16       g_gi[(size_t)TT * BB * NG];    // 201 MB f16

typedef __attribute__((ext_vector_type(8))) short    bfrag;   // 8 bf16 = 4 VGPR
typedef __attribute__((ext_vector_type(8))) _Float16 hfrag;   // 8 f16  = 4 VGPR
typedef __attribute__((ext_vector_type(4))) float    f32x4;

__device__ __forceinline__ unsigned short f2bf(float f) {
    unsigned u = __float_as_uint(f);
    return (unsigned short)((u + 0x7fffu + ((u >> 16) & 1u)) >> 16);   // RNE
}

// ---------------- phase 1a: x f32 -> bf16 ----------------
__global__ void cvt_x_kernel(const float* __restrict__ x) {
    const int n4 = TT * BB * II / 4;
    for (int i = blockIdx.x * blockDim.x + threadIdx.x; i < n4;
         i += gridDim.x * blockDim.x) {
        float4 v = reinterpret_cast<const float4*>(x)[i];
        ushort4 o;
        o.x = f2bf(v.x); o.y = f2bf(v.y); o.z = f2bf(v.z); o.w = f2bf(v.w);
        reinterpret_cast<ushort4*>(g_xbf)[i] = o;
    }
}

// ---------------- phase 1b: wihT [k][n] f32 -> wihB [n][k] bf16 ----------------
__global__ void cvt_wih_kernel(const float* __restrict__ wihT) {
    const int n = blockIdx.x;    // 0..767
    const int k = threadIdx.x;   // 0..255
    g_wihB[n * II + k] = f2bf(wihT[k * NG + n]);
}

// ---------------- phase 2: gi = x @ wihT + bias  (MFMA bf16, f16 out) ----------------
// Bias is folded here (additive to gi in all 3 gates; bn is NOT r-scaled in
// the reference, so the fold is exact) -> the recurrence kernel never
// touches bias: 3 fewer live VGPRs in the hot loop.
__global__ void __launch_bounds__(256) gi_gemm_kernel(const float* __restrict__ bias) {
    __shared__ unsigned short Ab[128 * 32];
    __shared__ unsigned short Bb[128 * 32];
    const int tid = threadIdx.x;
    const int mt = blockIdx.x / 6, nt = blockIdx.x % 6;
    const int m0 = mt * 128, n0 = nt * 128;
    const int l = tid & 63, w = tid >> 6;
    const int wr = w >> 1, wc = w & 1;
    const int srow = tid >> 2, scol = (tid & 3) * 8;

    f32x4 acc[4][4] = {};

    for (int ks = 0; ks < 8; ++ks) {
        const int k0 = ks * 32;
        __syncthreads();
        #pragma unroll
        for (int c = 0; c < 2; ++c) {
            const int row = c * 64 + srow;
            *reinterpret_cast<uint4*>(&Ab[row * 32 + scol]) =
                *reinterpret_cast<const uint4*>(&g_xbf[(size_t)(m0 + row) * II + k0 + scol]);
            *reinterpret_cast<uint4*>(&Bb[row * 32 + scol]) =
                *reinterpret_cast<const uint4*>(&g_wihB[(n0 + row) * II + k0 + scol]);
        }
        __syncthreads();
        bfrag af[4], bf[4];
        #pragma unroll
        for (int i = 0; i < 4; ++i) {
            af[i] = *reinterpret_cast<const bfrag*>(
                        &Ab[(wr * 64 + i * 16 + (l & 15)) * 32 + (l >> 4) * 8]);
            bf[i] = *reinterpret_cast<const bfrag*>(
                        &Bb[(wc * 64 + i * 16 + (l & 15)) * 32 + (l >> 4) * 8]);
        }
        #pragma unroll
        for (int mi = 0; mi < 4; ++mi)
            #pragma unroll
            for (int ni = 0; ni < 4; ++ni)
                acc[mi][ni] = __builtin_amdgcn_mfma_f32_16x16x32_bf16(
                                  af[mi], bf[ni], acc[mi][ni], 0, 0, 0);
    }
    #pragma unroll
    for (int mi = 0; mi < 4; ++mi) {
        const int grow = m0 + wr * 64 + mi * 16 + (l >> 4) * 4;
        #pragma unroll
        for (int ni = 0; ni < 4; ++ni) {
            const int gcol = n0 + wc * 64 + ni * 16 + (l & 15);
            const float bv = bias[gcol];
            #pragma unroll
            for (int q = 0; q < 4; ++q)
                g_gi[(size_t)(grow + q) * NG + gcol] = (_Float16)(acc[mi][ni][q] + bv);
        }
    }
}

// ---------------- phase 3: recurrence via MFMA, whh in B-fragments ----------------
// 128 WGs (one batch row) x 1024 threads (16 waves). Wave w owns j in
// [16w,16w+16) x {r,z,n}: 24 B-frags (f16) = 96 VGPR/lane held as MFMA
// operands. A = h as a 1x256 row: only LDS row 0 exists (1 KB ping-pong);
// A-frags are a 4-segment broadcast ds_read (addr depends only on g =
// lane>>4) + cndmask zeroing lanes ln15 != 0. C row 0 (lanes 0-15, reg 0)
// is gh. gi (f16, L3-resident, bias pre-folded) prefetched one step ahead.
//
// amdgpu_waves_per_eu(4,4): grid = 128 WGs on 256 CUs -> exactly 1 WG/CU
// (16 waves = 4 waves/SIMD), but r8's RA budgeted for 8 waves/SIMD (64
// regs) and spilled all 96 B-frag regs (WRITE_SIZE 64 MB of scratch).
// Pinning 4 waves/EU sets the budget to 128 regs/lane -- a budget the RA
// demonstrably produces (r3/r4/r6) and that fits 96+12+~15 live values.
#define LDB(NAME, CB, KT)                                                   \
    hfrag NAME;                                                             \
    _Pragma("unroll")                                                       \
    for (int e = 0; e < 8; ++e)                                             \
        NAME[e] = (_Float16)whhT[(size_t)((KT) * 32 + g * 8 + e) * NG + (CB) + ln15];

#define KSTEP(KT)                                                           \
    {                                                                       \
        const hfrag Av = *reinterpret_cast<const hfrag*>(hl + (KT) * 32 + (g << 3)); \
        const hfrag A  = (ln15 == 0) ? Av : hz;                             \
        accR = __builtin_amdgcn_mfma_f32_16x16x32_f16(A, BR##KT, accR, 0, 0, 0); \
        accZ = __builtin_amdgcn_mfma_f32_16x16x32_f16(A, BZ##KT, accZ, 0, 0, 0); \
        accN = __builtin_amdgcn_mfma_f32_16x16x32_f16(A, BN##KT, accN, 0, 0, 0); \
    }

__global__ void __launch_bounds__(1024)
__attribute__((amdgpu_waves_per_eu(4, 4)))
gru_rec_kernel(
    const float* __restrict__ h0, const float* __restrict__ whhT,
    float* __restrict__ out)
{
    __shared__ __align__(16) _Float16 hbuf[2][HH];   // 1 KB ping-pong h (f16)

    const int tid  = threadIdx.x;
    const int b    = blockIdx.x;
    const int w    = tid >> 6;          // wave 0..15
    const int l    = tid & 63;
    const int g    = l >> 4;            // k-chunk group 0..3
    const int ln15 = l & 15;            // B-col offset / A-row
    const int jb   = w << 4;            // wave's j base
    const int jj   = jb + ln15;         // this lane's j (used on g==0)

    // --- whh B-fragments: 3 gates x 8 k-tiles, named SSA (f16) ---
    LDB(BR0, jb, 0) LDB(BR1, jb, 1) LDB(BR2, jb, 2) LDB(BR3, jb, 3)
    LDB(BR4, jb, 4) LDB(BR5, jb, 5) LDB(BR6, jb, 6) LDB(BR7, jb, 7)
    LDB(BZ0, HH + jb, 0) LDB(BZ1, HH + jb, 1) LDB(BZ2, HH + jb, 2) LDB(BZ3, HH + jb, 3)
    LDB(BZ4, HH + jb, 4) LDB(BZ5, HH + jb, 5) LDB(BZ6, HH + jb, 6) LDB(BZ7, HH + jb, 7)
    LDB(BN0, 2*HH + jb, 0) LDB(BN1, 2*HH + jb, 1) LDB(BN2, 2*HH + jb, 2) LDB(BN3, 2*HH + jb, 3)
    LDB(BN4, 2*HH + jb, 4) LDB(BN5, 2*HH + jb, 5) LDB(BN6, 2*HH + jb, 6) LDB(BN7, 2*HH + jb, 7)

    const hfrag hz = {};

    // --- init LDS row 0 with h0; hprev tracked in-register on g==0 lanes ---
    float hprev = h0[b * HH + jj];
    if (tid < 256) hbuf[0][tid] = (_Float16)h0[b * HH + tid];
    __syncthreads();

    // gi prefetch registers (bias pre-folded), primed for t=0
    const _Float16* gb0 = g_gi + (size_t)b * NG;
    float gR = (float)gb0[jj], gZ = (float)gb0[HH + jj], gN = (float)gb0[2 * HH + jj];

    for (int t = 0; t < TT; ++t) {
        const _Float16* hl  = hbuf[t & 1];
        _Float16*       hn_ = hbuf[(t & 1) ^ 1];

        // prefetch gi[t+1] (consumed next iteration)
        float nR = gR, nZ = gZ, nN = gN;
        if (t + 1 < TT) {
            const _Float16* gn = g_gi + ((size_t)(t + 1) * BB + b) * NG;
            nR = (float)gn[jj]; nZ = (float)gn[HH + jj]; nN = (float)gn[2 * HH + jj];
        }

        // gh = h @ whh for this wave's 16 j x 3 gates
        f32x4 accR = {0.f, 0.f, 0.f, 0.f};
        f32x4 accZ = {0.f, 0.f, 0.f, 0.f};
        f32x4 accN = {0.f, 0.f, 0.f, 0.f};
        KSTEP(0) KSTEP(1) KSTEP(2) KSTEP(3)
        KSTEP(4) KSTEP(5) KSTEP(6) KSTEP(7)

        // epilogue: C row 0 = acc*[0] on lanes g==0 (col = ln15)
        const float r  = 1.f / (1.f + __expf(-(accR[0] + gR)));
        const float z  = 1.f / (1.f + __expf(-(accZ[0] + gZ)));
        const float e  = __expf(2.f * (gN + r * accN[0]));   // tanh
        const float n  = 1.f - 2.f / (e + 1.f);
        const float hv = (1.f - z) * n + z * hprev;
        if (g == 0) {
            hprev = hv;
            hn_[jj] = (_Float16)hv;
            if (t == TT - 1) out[b * HH + jj] = hv;
        }

        gR = nR; gZ = nZ; gN = nN;
        __syncthreads();
    }
}

extern "C" void kernel_launch(void* const* d_in, const int* in_sizes, int n_in,
                              void* d_out, int out_size, void* d_ws, size_t ws_size,
                              hipStream_t stream) {
    const float* x    = (const float*)d_in[0];
    const float* h0   = (const float*)d_in[1];
    const float* wihT = (const float*)d_in[2];
    const float* whhT = (const float*)d_in[3];
    const float* bias = (const float*)d_in[4];
    float*       out  = (float*)d_out;

    cvt_x_kernel<<<2048, 256, 0, stream>>>(x);
    cvt_wih_kernel<<<NG, 256, 0, stream>>>(wihT);
    gi_gemm_kernel<<<1024 * 6, 256, 0, stream>>>(bias);
    gru_rec_kernel<<<BB, 1024, 0, stream>>>(h0, whhT, out);
}